// Round 4
// baseline (1702.590 us; speedup 1.0000x reference)
//
#include <hip/hip_runtime.h>

#define NN 100000
#define EE 1600000
#define HH 128
#define MM 256
#define LL 6
#define GG 512
#define SCAN_NB ((NN + 1023) / 1024)

typedef __attribute__((ext_vector_type(8))) short short8;
typedef __attribute__((ext_vector_type(4))) float floatx4;

__device__ __forceinline__ float swishf(float v) {
    return v / (1.0f + __expf(-v));
}

__device__ __forceinline__ unsigned short f2bf(float f) {
    unsigned u = __builtin_bit_cast(unsigned, f);
    unsigned r = u + 0x7FFFu + ((u >> 16) & 1u);
    return (unsigned short)(r >> 16);
}

__device__ __forceinline__ float bf2f(unsigned short u) {
    return __builtin_bit_cast(float, (unsigned)u << 16);
}

__device__ __forceinline__ float2 bf2f2(unsigned u) {
    float2 r;
    r.x = __builtin_bit_cast(float, u << 16);
    r.y = __builtin_bit_cast(float, u & 0xFFFF0000u);
    return r;
}

// blocked activation layout: [C/16][N][16] bf16
__device__ __forceinline__ size_t blkaddr(int c, int r) {
    return ((size_t)(c >> 4) * NN + r) * 16 + (c & 15);
}

// h (blocked bf16) = z_embed[z[n]] + x[:,1:]@ew^T + eb
__global__ void k_embed(const float* __restrict__ x, const float* __restrict__ z_embed,
                        const float* __restrict__ ew, const float* __restrict__ eb,
                        unsigned short* __restrict__ hb) {
    int idx = blockIdx.x * blockDim.x + threadIdx.x;
    if (idx >= NN * 32) return;
    int n = idx >> 5;
    int c0 = (idx & 31) << 2;
    const float* xr = x + (size_t)n * 4;
    int z = (int)xr[0];
    float x1 = xr[1], x2 = xr[2], x3 = xr[3];
    const float* ze = z_embed + (size_t)z * HH + c0;
    float o[4];
#pragma unroll
    for (int j = 0; j < 4; ++j) {
        int c = c0 + j;
        o[j] = ze[j] + x1 * ew[c * 3 + 0] + x2 * ew[c * 3 + 1] + x3 * ew[c * 3 + 2] + eb[c];
    }
    uint2 p;
    p.x = (unsigned)f2bf(o[0]) | ((unsigned)f2bf(o[1]) << 16);
    p.y = (unsigned)f2bf(o[2]) | ((unsigned)f2bf(o[3]) << 16);
    *(uint2*)(hb + blkaddr(c0, n)) = p;
}

// cast 3 weight tensors fp32->bf16 in one launch
__global__ void k_f2bf3(const float* __restrict__ s1, unsigned short* __restrict__ d1, int n1,
                        const float* __restrict__ s2, unsigned short* __restrict__ d2, int n2,
                        const float* __restrict__ s3, unsigned short* __restrict__ d3, int n3) {
    int i = blockIdx.x * blockDim.x + threadIdx.x;
    if (i < n1) {
        d1[i] = f2bf(s1[i]);
    } else if (i < n1 + n2) {
        d2[i - n1] = f2bf(s2[i - n1]);
    } else if (i < n1 + n2 + n3) {
        d3[i - n1 - n2] = f2bf(s3[i - n1 - n2]);
    }
}

// XCD-partitioned degree count
__global__ __launch_bounds__(256) void k_degree_p(const int* __restrict__ dst,
                                                  int* __restrict__ deg) {
    int part = blockIdx.x & 7;
    int blk = blockIdx.x >> 3;
    int nb = gridDim.x >> 3;
    int lo = (int)((long long)part * NN / 8);
    int hi = (int)((long long)(part + 1) * NN / 8);
    for (int e = blk * 256 + threadIdx.x; e < EE; e += nb * 256) {
        int d = dst[e];
        if (d >= lo && d < hi) atomicAdd(&deg[d], 1);
    }
}

__global__ void k_dinv(const int* __restrict__ deg, float* __restrict__ dinv) {
    int n = blockIdx.x * blockDim.x + threadIdx.x;
    if (n < NN) dinv[n] = rsqrtf((float)(deg[n] + 1));
}

__global__ void k_scan1(const int* __restrict__ deg, int* __restrict__ bsum) {
    __shared__ int sd[256];
    int t = threadIdx.x;
    int base = blockIdx.x * 1024 + t * 4;
    int s = 0;
#pragma unroll
    for (int j = 0; j < 4; ++j) {
        int i = base + j;
        if (i < NN) s += deg[i];
    }
    sd[t] = s;
    __syncthreads();
    for (int off = 128; off > 0; off >>= 1) {
        if (t < off) sd[t] += sd[t + off];
        __syncthreads();
    }
    if (t == 0) bsum[blockIdx.x] = sd[0];
}

__global__ void k_scan2(const int* __restrict__ bsum, int* __restrict__ boff) {
    __shared__ int sd[128];
    int t = threadIdx.x;
    int v = (t < SCAN_NB) ? bsum[t] : 0;
    sd[t] = v;
    __syncthreads();
    for (int off = 1; off < 128; off <<= 1) {
        int u = (t >= off) ? sd[t - off] : 0;
        __syncthreads();
        sd[t] += u;
        __syncthreads();
    }
    boff[t] = sd[t] - v;  // exclusive
}

__global__ void k_scan3(const int* __restrict__ deg, const int* __restrict__ boff,
                        int* __restrict__ rowptr) {
    __shared__ int sd[256];
    int t = threadIdx.x;
    int base = blockIdx.x * 1024 + t * 4;
    int v[4];
    int s = 0;
#pragma unroll
    for (int j = 0; j < 4; ++j) {
        int i = base + j;
        v[j] = (i < NN) ? deg[i] : 0;
        s += v[j];
    }
    sd[t] = s;
    __syncthreads();
    for (int off = 1; off < 256; off <<= 1) {
        int u = (t >= off) ? sd[t - off] : 0;
        __syncthreads();
        sd[t] += u;
        __syncthreads();
    }
    int run = boff[blockIdx.x] + sd[t] - s;
#pragma unroll
    for (int j = 0; j < 4; ++j) {
        int i = base + j;
        if (i < NN) rowptr[i] = run;
        if (i == NN - 1) rowptr[NN] = run + v[j];
        run += v[j];
    }
}

// XCD-partitioned CSR fill
__global__ __launch_bounds__(256) void k_fill_p(const int* __restrict__ ei,
                                                const int* __restrict__ rowptr,
                                                int* __restrict__ cursor,
                                                int* __restrict__ col) {
    int part = blockIdx.x & 7;
    int blk = blockIdx.x >> 3;
    int nb = gridDim.x >> 3;
    int lo = (int)((long long)part * NN / 8);
    int hi = (int)((long long)(part + 1) * NN / 8);
    for (int e = blk * 256 + threadIdx.x; e < EE; e += nb * 256) {
        int d = ei[EE + e];
        if (d >= lo && d < hi) {
            int p = atomicAdd(&cursor[d], 1);
            col[rowptr[d] + p] = ei[e];
        }
    }
}

__global__ void k_gptr(const int* __restrict__ batch, int* __restrict__ gptr) {
    int n = blockIdx.x * blockDim.x + threadIdx.x;
    if (n >= NN) return;
    int b = batch[n];
    int pb = (n == 0) ? -1 : batch[n - 1];
    for (int g = pb + 1; g <= b; ++g) gptr[g] = n;
    if (n == NN - 1) {
        for (int g = b + 1; g <= GG; ++g) gptr[g] = NN;
    }
}

// Register-resident MFMA GEMM (no LDS, no barriers). A is blocked bf16 [K/16][N][16],
// B is row-major bf16 [Cout][K] (weights, L2-resident). fp32 accumulate.
// EPI 0: Cb = bf16(acc * dinv[r])                 (aux = dinv fp32)
// EPI 1: Cb = bf16(swish(acc + bias))
// EPI 2: o = swish(acc+bias) + res_blk[r,c]; Cb = bf16(o) blocked; if(writeF) Cf row-major
template <int K, int EPI>
__global__ __launch_bounds__(256) void k_gemm_reg(const unsigned short* __restrict__ A,
                                                  const unsigned short* __restrict__ B,
                                                  const float* __restrict__ bias,
                                                  const void* aux, float* Cf,
                                                  unsigned short* __restrict__ Cb, int writeF) {
    const int tid = threadIdx.x;
    const int wave = tid >> 6;
    const int lane = tid & 63;
    const int quad = lane >> 4;
    const int l16 = lane & 15;
    const int wr = (wave & 1) << 6;
    const int wc = (wave >> 1) << 6;
    const int rowBase = blockIdx.x * 128;
    const int colBase = blockIdx.y * 128;

    floatx4 acc[4][4];
    const floatx4 zed = {0.f, 0.f, 0.f, 0.f};
#pragma unroll
    for (int i = 0; i < 4; ++i)
#pragma unroll
        for (int j = 0; j < 4; ++j) acc[i][j] = zed;

    int ar[4];
#pragma unroll
    for (int i = 0; i < 4; ++i) {
        int r = rowBase + wr + (i << 4) + l16;
        ar[i] = r < NN ? r : NN - 1;
    }
    const unsigned short* Bbase = B + (size_t)(colBase + wc + l16) * K;

#pragma unroll 4
    for (int kc = 0; kc < K; kc += 32) {
        int k = kc + (quad << 3);
        short8 a[4], b[4];
#pragma unroll
        for (int i = 0; i < 4; ++i)
            a[i] = *(const short8*)(A + ((size_t)(k >> 4) * NN + ar[i]) * 16 + (k & 15));
#pragma unroll
        for (int j = 0; j < 4; ++j)
            b[j] = *(const short8*)(Bbase + (size_t)(j << 4) * K + k);
#pragma unroll
        for (int i = 0; i < 4; ++i)
#pragma unroll
            for (int j = 0; j < 4; ++j)
                acc[i][j] =
                    __builtin_amdgcn_mfma_f32_16x16x32_bf16(a[i], b[j], acc[i][j], 0, 0, 0);
    }

    float bv[4];
    if (EPI >= 1) {
#pragma unroll
        for (int j = 0; j < 4; ++j) bv[j] = bias[colBase + wc + (j << 4) + l16];
    }
#pragma unroll
    for (int i = 0; i < 4; ++i) {
#pragma unroll
        for (int reg = 0; reg < 4; ++reg) {
            int r = rowBase + wr + (i << 4) + (quad << 2) + reg;
            if (r < NN) {
                if (EPI == 0) {
                    float dv = ((const float*)aux)[r];
#pragma unroll
                    for (int j = 0; j < 4; ++j) {
                        int c = colBase + wc + (j << 4) + l16;
                        Cb[blkaddr(c, r)] = f2bf(acc[i][j][reg] * dv);
                    }
                } else if (EPI == 1) {
#pragma unroll
                    for (int j = 0; j < 4; ++j) {
                        int c = colBase + wc + (j << 4) + l16;
                        Cb[blkaddr(c, r)] = f2bf(swishf(acc[i][j][reg] + bv[j]));
                    }
                } else {
                    const unsigned short* res = (const unsigned short*)aux;
#pragma unroll
                    for (int j = 0; j < 4; ++j) {
                        int c = colBase + wc + (j << 4) + l16;
                        float o = swishf(acc[i][j][reg] + bv[j]) + bf2f(res[blkaddr(c, r)]);
                        Cb[blkaddr(c, r)] = f2bf(o);
                        if (writeF) Cf[(size_t)r * HH + c] = o;
                    }
                }
            }
        }
    }
}

// XCD-local feature-blocked aggregation. part p (= blockIdx&7 -> XCD p) gathers only
// y slice p ([NN][16] bf16 = 3.2 MB, L2-resident). 8 lanes/node * 4 B = 32 B slice row.
// agg_blk[p][d][:] = bf16( dinv[d] * (sum_src y_blk[p][src] + y_blk[p][d]) + cb[p*16..] )
__global__ __launch_bounds__(256) void k_agg(const unsigned short* __restrict__ y,
                                             const int* __restrict__ rowptr,
                                             const int* __restrict__ col,
                                             const float* __restrict__ dinv,
                                             const float* __restrict__ cb,
                                             unsigned short* __restrict__ agg) {
    int p = blockIdx.x & 7;
    int chunk = blockIdx.x >> 3;
    int wave = threadIdx.x >> 6;
    int lane = threadIdx.x & 63;
    int g8 = lane >> 3;
    int sub = lane & 7;
    int d = chunk * 32 + (wave << 3) + g8;
    if (d >= NN) return;
    const unsigned* ys = (const unsigned*)y + (size_t)p * NN * 8;
    float2 acc = bf2f2(ys[(size_t)d * 8 + sub]);
    int beg = rowptr[d];
    int end = rowptr[d + 1];
    int e = beg;
    for (; e + 3 < end; e += 4) {
        int s0 = col[e], s1 = col[e + 1], s2 = col[e + 2], s3 = col[e + 3];
        float2 v0 = bf2f2(ys[(size_t)s0 * 8 + sub]);
        float2 v1 = bf2f2(ys[(size_t)s1 * 8 + sub]);
        float2 v2 = bf2f2(ys[(size_t)s2 * 8 + sub]);
        float2 v3 = bf2f2(ys[(size_t)s3 * 8 + sub]);
        acc.x += (v0.x + v1.x) + (v2.x + v3.x);
        acc.y += (v0.y + v1.y) + (v2.y + v3.y);
    }
    for (; e < end; ++e) {
        float2 v0 = bf2f2(ys[(size_t)col[e] * 8 + sub]);
        acc.x += v0.x;
        acc.y += v0.y;
    }
    float dv = dinv[d];
    int c = p * 16 + sub * 2;
    float ox = acc.x * dv + cb[c];
    float oy = acc.y * dv + cb[c + 1];
    unsigned pk = (unsigned)f2bf(ox) | ((unsigned)f2bf(oy) << 16);
    ((unsigned*)agg)[(size_t)p * NN * 8 + (size_t)d * 8 + sub] = pk;
}

// per-(graph, part) stats from blocked agg (reads XCD-local slice)
__global__ __launch_bounds__(256) void k_stats(const unsigned short* __restrict__ agg,
                                               const int* __restrict__ gptr,
                                               const float* __restrict__ ms,
                                               float* __restrict__ gmean,
                                               float* __restrict__ grstd) {
    __shared__ float s1[256];
    __shared__ float s2[256];
    int p = blockIdx.x & 7;
    int g = blockIdx.x >> 3;
    int t = threadIdx.x;
    int cc = t & 15;
    int pr = t >> 4;
    int beg = gptr[g];
    int end = gptr[g + 1];
    const unsigned short* ap = agg + (size_t)p * NN * 16;
    float S1 = 0.f, S2 = 0.f;
    for (int n = beg + pr; n < end; n += 16) {
        float v = bf2f(ap[(size_t)n * 16 + cc]);
        S1 += v;
        S2 += v * v;
    }
    s1[t] = S1;
    s2[t] = S2;
    __syncthreads();
    if (t < 16) {
        float T1 = 0.f, T2 = 0.f;
#pragma unroll
        for (int k = 0; k < 16; ++k) {
            T1 += s1[k * 16 + t];
            T2 += s2[k * 16 + t];
        }
        int cnt = end - beg;
        float inv = 1.0f / (float)(cnt > 0 ? cnt : 1);
        float m = T1 * inv;
        int c = p * 16 + t;
        float msc = ms[c];
        float var = T2 * inv - msc * (2.0f - msc) * m * m;
        gmean[g * HH + c] = m;
        grstd[g * HH + c] = rsqrtf(var + 1e-5f);
    }
}

// part-partitioned norm+swish: reads XCD-local agg slice, writes blocked ha slice
__global__ __launch_bounds__(256) void k_normswish(const unsigned short* __restrict__ agg,
                                                   const int* __restrict__ batch,
                                                   const float* __restrict__ gamma,
                                                   const float* __restrict__ beta,
                                                   const float* __restrict__ ms,
                                                   const float* __restrict__ gmean,
                                                   const float* __restrict__ grstd,
                                                   unsigned short* __restrict__ ha) {
    int p = blockIdx.x & 7;
    int chunk = blockIdx.x >> 3;
    int t = threadIdx.x;
    int n = chunk * 64 + (t >> 2);
    if (n >= NN) return;
    int cc0 = (t & 3) << 2;
    int g = batch[n];
    size_t base = (size_t)p * NN * 16 + (size_t)n * 16 + cc0;
    uint2 ain = *(const uint2*)(agg + base);
    float2 a01 = bf2f2(ain.x);
    float2 a23 = bf2f2(ain.y);
    float av[4] = {a01.x, a01.y, a23.x, a23.y};
    unsigned short o[4];
#pragma unroll
    for (int j = 0; j < 4; ++j) {
        int c = p * 16 + cc0 + j;
        float sub = av[j] - ms[c] * gmean[g * HH + c];
        float hn = gamma[c] * sub * grstd[g * HH + c] + beta[c];
        o[j] = f2bf(swishf(hn));
    }
    uint2 pk;
    pk.x = (unsigned)o[0] | ((unsigned)o[1] << 16);
    pk.y = (unsigned)o[2] | ((unsigned)o[3] << 16);
    *(uint2*)(ha + base) = pk;
}

extern "C" void kernel_launch(void* const* d_in, const int* in_sizes, int n_in,
                              void* d_out, int out_size, void* d_ws, size_t ws_size,
                              hipStream_t stream) {
    const float* x = (const float*)d_in[0];
    const int* ei = (const int*)d_in[1];
    const int* batch = (const int*)d_in[2];
    const float* z_embed = (const float*)d_in[3];
    const float* extra_w = (const float*)d_in[4];
    const float* extra_b = (const float*)d_in[5];
    const float* conv_w = (const float*)d_in[6];
    const float* conv_b = (const float*)d_in[7];
    const float* gamma = (const float*)d_in[8];
    const float* beta = (const float*)d_in[9];
    const float* mean_scale = (const float*)d_in[10];
    const float* mlp_w1 = (const float*)d_in[11];
    const float* mlp_b1 = (const float*)d_in[12];
    const float* mlp_w2 = (const float*)d_in[13];
    const float* mlp_b2 = (const float*)d_in[14];
    float* h_out = (float*)d_out;

    char* wsB = (char*)d_ws;
    size_t off = 0;
    auto alloc = [&](size_t bytes) -> void* {
        void* p = (void*)(wsB + off);
        off = (off + bytes + 255) & ~(size_t)255;
        return p;
    };
    float* dinv = (float*)alloc((size_t)NN * 4);
    int* deg = (int*)alloc((size_t)NN * 4);
    int* cursor = (int*)alloc((size_t)NN * 4);
    int* rowptr = (int*)alloc((size_t)(NN + 1) * 4);
    int* bsum = (int*)alloc(128 * 4);
    int* boff = (int*)alloc(128 * 4);
    int* col = (int*)alloc((size_t)EE * 4);
    int* gptr = (int*)alloc((size_t)(GG + 1) * 4);
    float* gmean = (float*)alloc((size_t)GG * HH * 4);
    float* grstd = (float*)alloc((size_t)GG * HH * 4);
    unsigned short* wb =
        (unsigned short*)alloc((size_t)(LL * (HH * HH + MM * HH + HH * MM)) * 2);
    unsigned short* cwb = wb;
    unsigned short* w1b = wb + (size_t)LL * HH * HH;
    unsigned short* w2b = w1b + (size_t)LL * MM * HH;
    unsigned short* hb = (unsigned short*)alloc((size_t)NN * HH * 2);    // blocked residual
    unsigned short* ybuf = (unsigned short*)alloc((size_t)NN * HH * 2);  // blocked y then ha
    unsigned short* tb = (unsigned short*)alloc((size_t)NN * MM * 2);    // blocked t / agg
    unsigned short* aggb = tb;  // blocked agg [8][NN][16] (consumed before t written)

    hipMemsetAsync(deg, 0, (size_t)NN * 4, stream);
    hipMemsetAsync(cursor, 0, (size_t)NN * 4, stream);

    k_embed<<<(NN * 32 + 255) / 256, 256, 0, stream>>>(x, z_embed, extra_w, extra_b, hb);
    {
        int n1 = LL * HH * HH, n2 = LL * MM * HH, n3 = LL * HH * MM;
        int nt = n1 + n2 + n3;
        k_f2bf3<<<(nt + 255) / 256, 256, 0, stream>>>(conv_w, cwb, n1, mlp_w1, w1b, n2,
                                                      mlp_w2, w2b, n3);
    }
    k_degree_p<<<1024, 256, 0, stream>>>(ei + EE, deg);
    k_dinv<<<(NN + 255) / 256, 256, 0, stream>>>(deg, dinv);
    k_scan1<<<SCAN_NB, 256, 0, stream>>>(deg, bsum);
    k_scan2<<<1, 128, 0, stream>>>(bsum, boff);
    k_scan3<<<SCAN_NB, 256, 0, stream>>>(deg, boff, rowptr);
    k_fill_p<<<1024, 256, 0, stream>>>(ei, rowptr, cursor, col);
    k_gptr<<<(NN + 255) / 256, 256, 0, stream>>>(batch, gptr);

    dim3 g1((NN + 127) / 128, 1);
    dim3 g2((NN + 127) / 128, 2);
    int aggGrid = ((NN + 31) / 32) * 8;
    int nsGrid = ((NN + 63) / 64) * 8;
    for (int i = 0; i < LL; ++i) {
        k_gemm_reg<HH, 0><<<g1, 256, 0, stream>>>(hb, cwb + (size_t)i * HH * HH, nullptr,
                                                  dinv, nullptr, ybuf, 0);
        k_agg<<<aggGrid, 256, 0, stream>>>(ybuf, rowptr, col, dinv, conv_b + (size_t)i * HH,
                                           aggb);
        k_stats<<<GG * 8, 256, 0, stream>>>(aggb, gptr, mean_scale + (size_t)i * HH, gmean,
                                            grstd);
        k_normswish<<<nsGrid, 256, 0, stream>>>(aggb, batch, gamma + (size_t)i * HH,
                                                beta + (size_t)i * HH,
                                                mean_scale + (size_t)i * HH, gmean, grstd,
                                                ybuf);
        k_gemm_reg<HH, 1><<<g2, 256, 0, stream>>>(ybuf, w1b + (size_t)i * MM * HH,
                                                  mlp_b1 + (size_t)i * MM, nullptr, nullptr,
                                                  tb, 0);
        k_gemm_reg<MM, 2><<<g1, 256, 0, stream>>>(tb, w2b + (size_t)i * HH * MM,
                                                  mlp_b2 + (size_t)i * HH, hb, h_out, hb,
                                                  i == LL - 1 ? 1 : 0);
    }
}

// Round 5
// 1532.303 us; speedup vs baseline: 1.1111x; 1.1111x over previous
//
#include <hip/hip_runtime.h>

#define NN 100000
#define EE 1600000
#define HH 128
#define MM 256
#define LL 6
#define GG 512
#define SCAN_NB ((NN + 1023) / 1024)

typedef __attribute__((ext_vector_type(8))) short short8;
typedef __attribute__((ext_vector_type(4))) float floatx4;

__device__ __forceinline__ float swishf(float v) {
    return v / (1.0f + __expf(-v));
}

__device__ __forceinline__ unsigned short f2bf(float f) {
    unsigned u = __builtin_bit_cast(unsigned, f);
    unsigned r = u + 0x7FFFu + ((u >> 16) & 1u);
    return (unsigned short)(r >> 16);
}

__device__ __forceinline__ float bf2f(unsigned short u) {
    return __builtin_bit_cast(float, (unsigned)u << 16);
}

__device__ __forceinline__ float2 bf2f2(unsigned u) {
    float2 r;
    r.x = __builtin_bit_cast(float, u << 16);
    r.y = __builtin_bit_cast(float, u & 0xFFFF0000u);
    return r;
}

// h[n,c] (row-major bf16) = z_embed[z[n],c] + x[:,1:]@ew^T + eb
__global__ void k_embed(const float* __restrict__ x, const float* __restrict__ z_embed,
                        const float* __restrict__ ew, const float* __restrict__ eb,
                        unsigned short* __restrict__ hb) {
    int idx = blockIdx.x * blockDim.x + threadIdx.x;
    if (idx >= NN * 32) return;
    int n = idx >> 5;
    int c0 = (idx & 31) << 2;
    const float* xr = x + (size_t)n * 4;
    int z = (int)xr[0];
    float x1 = xr[1], x2 = xr[2], x3 = xr[3];
    const float* ze = z_embed + (size_t)z * HH + c0;
    float o[4];
#pragma unroll
    for (int j = 0; j < 4; ++j) {
        int c = c0 + j;
        o[j] = ze[j] + x1 * ew[c * 3 + 0] + x2 * ew[c * 3 + 1] + x3 * ew[c * 3 + 2] + eb[c];
    }
    uint2 p;
    p.x = (unsigned)f2bf(o[0]) | ((unsigned)f2bf(o[1]) << 16);
    p.y = (unsigned)f2bf(o[2]) | ((unsigned)f2bf(o[3]) << 16);
    *(uint2*)(hb + (size_t)n * HH + c0) = p;
}

// cast 3 weight tensors fp32->bf16 in one launch
__global__ void k_f2bf3(const float* __restrict__ s1, unsigned short* __restrict__ d1, int n1,
                        const float* __restrict__ s2, unsigned short* __restrict__ d2, int n2,
                        const float* __restrict__ s3, unsigned short* __restrict__ d3, int n3) {
    int i = blockIdx.x * blockDim.x + threadIdx.x;
    if (i < n1) {
        d1[i] = f2bf(s1[i]);
    } else if (i < n1 + n2) {
        d2[i - n1] = f2bf(s2[i - n1]);
    } else if (i < n1 + n2 + n3) {
        d3[i - n1 - n2] = f2bf(s3[i - n1 - n2]);
    }
}

// XCD-partitioned degree count
__global__ __launch_bounds__(256) void k_degree_p(const int* __restrict__ dst,
                                                  int* __restrict__ deg) {
    int part = blockIdx.x & 7;
    int blk = blockIdx.x >> 3;
    int nb = gridDim.x >> 3;
    int lo = (int)((long long)part * NN / 8);
    int hi = (int)((long long)(part + 1) * NN / 8);
    for (int e = blk * 256 + threadIdx.x; e < EE; e += nb * 256) {
        int d = dst[e];
        if (d >= lo && d < hi) atomicAdd(&deg[d], 1);
    }
}

__global__ void k_dinv(const int* __restrict__ deg, float* __restrict__ dinv) {
    int n = blockIdx.x * blockDim.x + threadIdx.x;
    if (n < NN) dinv[n] = rsqrtf((float)(deg[n] + 1));
}

__global__ void k_scan1(const int* __restrict__ deg, int* __restrict__ bsum) {
    __shared__ int sd[256];
    int t = threadIdx.x;
    int base = blockIdx.x * 1024 + t * 4;
    int s = 0;
#pragma unroll
    for (int j = 0; j < 4; ++j) {
        int i = base + j;
        if (i < NN) s += deg[i];
    }
    sd[t] = s;
    __syncthreads();
    for (int off = 128; off > 0; off >>= 1) {
        if (t < off) sd[t] += sd[t + off];
        __syncthreads();
    }
    if (t == 0) bsum[blockIdx.x] = sd[0];
}

__global__ void k_scan2(const int* __restrict__ bsum, int* __restrict__ boff) {
    __shared__ int sd[128];
    int t = threadIdx.x;
    int v = (t < SCAN_NB) ? bsum[t] : 0;
    sd[t] = v;
    __syncthreads();
    for (int off = 1; off < 128; off <<= 1) {
        int u = (t >= off) ? sd[t - off] : 0;
        __syncthreads();
        sd[t] += u;
        __syncthreads();
    }
    boff[t] = sd[t] - v;  // exclusive
}

__global__ void k_scan3(const int* __restrict__ deg, const int* __restrict__ boff,
                        int* __restrict__ rowptr) {
    __shared__ int sd[256];
    int t = threadIdx.x;
    int base = blockIdx.x * 1024 + t * 4;
    int v[4];
    int s = 0;
#pragma unroll
    for (int j = 0; j < 4; ++j) {
        int i = base + j;
        v[j] = (i < NN) ? deg[i] : 0;
        s += v[j];
    }
    sd[t] = s;
    __syncthreads();
    for (int off = 1; off < 256; off <<= 1) {
        int u = (t >= off) ? sd[t - off] : 0;
        __syncthreads();
        sd[t] += u;
        __syncthreads();
    }
    int run = boff[blockIdx.x] + sd[t] - s;
#pragma unroll
    for (int j = 0; j < 4; ++j) {
        int i = base + j;
        if (i < NN) rowptr[i] = run;
        if (i == NN - 1) rowptr[NN] = run + v[j];
        run += v[j];
    }
}

// XCD-partitioned CSR fill
__global__ __launch_bounds__(256) void k_fill_p(const int* __restrict__ ei,
                                                const int* __restrict__ rowptr,
                                                int* __restrict__ cursor,
                                                int* __restrict__ col) {
    int part = blockIdx.x & 7;
    int blk = blockIdx.x >> 3;
    int nb = gridDim.x >> 3;
    int lo = (int)((long long)part * NN / 8);
    int hi = (int)((long long)(part + 1) * NN / 8);
    for (int e = blk * 256 + threadIdx.x; e < EE; e += nb * 256) {
        int d = ei[EE + e];
        if (d >= lo && d < hi) {
            int p = atomicAdd(&cursor[d], 1);
            col[rowptr[d] + p] = ei[e];
        }
    }
}

__global__ void k_gptr(const int* __restrict__ batch, int* __restrict__ gptr) {
    int n = blockIdx.x * blockDim.x + threadIdx.x;
    if (n >= NN) return;
    int b = batch[n];
    int pb = (n == 0) ? -1 : batch[n - 1];
    for (int g = pb + 1; g <= b; ++g) gptr[g] = n;
    if (n == NN - 1) {
        for (int g = b + 1; g <= GG; ++g) gptr[g] = NN;
    }
}

// Weights-stationary MFMA GEMM: B tile (128 cols x K) staged to LDS once (one
// barrier), A fragments global->registers (coalesced 16B, full lines), then a
// barrier-free K-loop of MFMAs. A row-major bf16 [N][K], B row-major bf16 [Cout][K].
// EPI 0: Cb = bf16(acc * dinv[r])                 (aux = dinv fp32)
// EPI 1: Cb = bf16(swish(acc + bias))
// EPI 2: o = swish(acc+bias) + res_bf[r,c]; Cb = bf16(o); if(writeF) Cf fp32 row-major
template <int K, int EPI>
__global__ __launch_bounds__(256) void k_gemm(const unsigned short* __restrict__ A,
                                              const unsigned short* __restrict__ B,
                                              const float* __restrict__ bias, const void* aux,
                                              float* Cf, unsigned short* __restrict__ Cb,
                                              int writeF) {
    __shared__ unsigned short Bs[128][K + 8];  // pitch (K+8)*2 B: 16B-aligned rows, 2-way-max banks
    const int tid = threadIdx.x;
    const int wave = tid >> 6;
    const int lane = tid & 63;
    const int quad = lane >> 4;
    const int l16 = lane & 15;
    const int wr = (wave & 1) << 6;
    const int wc = (wave >> 1) << 6;
    const int rowBase = blockIdx.x * 128;
    const int colBase = blockIdx.y * 128;

    // stage B tile to LDS (once)
#pragma unroll
    for (int i = tid; i < 128 * (K / 8); i += 256) {
        int r = i / (K / 8);
        int kk = (i % (K / 8)) * 8;
        *(uint4*)(&Bs[r][kk]) = *(const uint4*)(B + (size_t)(colBase + r) * K + kk);
    }

    floatx4 acc[4][4];
    const floatx4 zed = {0.f, 0.f, 0.f, 0.f};
#pragma unroll
    for (int i = 0; i < 4; ++i)
#pragma unroll
        for (int j = 0; j < 4; ++j) acc[i][j] = zed;

    int ar[4];
#pragma unroll
    for (int i = 0; i < 4; ++i) {
        int r = rowBase + wr + (i << 4) + l16;
        ar[i] = r < NN ? r : NN - 1;
    }

    __syncthreads();  // B ready; no further barriers

#pragma unroll
    for (int ks = 0; ks < K / 32; ++ks) {
        int k = (ks << 5) + (quad << 3);
        short8 a[4], b[4];
#pragma unroll
        for (int i = 0; i < 4; ++i) a[i] = *(const short8*)(A + (size_t)ar[i] * K + k);
#pragma unroll
        for (int j = 0; j < 4; ++j) b[j] = *(const short8*)(&Bs[wc + (j << 4) + l16][k]);
#pragma unroll
        for (int i = 0; i < 4; ++i)
#pragma unroll
            for (int j = 0; j < 4; ++j)
                acc[i][j] =
                    __builtin_amdgcn_mfma_f32_16x16x32_bf16(a[i], b[j], acc[i][j], 0, 0, 0);
    }

    const int Cout = gridDim.y << 7;
    float bv[4];
    if (EPI >= 1) {
#pragma unroll
        for (int j = 0; j < 4; ++j) bv[j] = bias[colBase + wc + (j << 4) + l16];
    }
#pragma unroll
    for (int i = 0; i < 4; ++i) {
#pragma unroll
        for (int reg = 0; reg < 4; ++reg) {
            int r = rowBase + wr + (i << 4) + (quad << 2) + reg;
            if (r < NN) {
                if (EPI == 0) {
                    float dv = ((const float*)aux)[r];
#pragma unroll
                    for (int j = 0; j < 4; ++j) {
                        int c = colBase + wc + (j << 4) + l16;
                        Cb[(size_t)r * Cout + c] = f2bf(acc[i][j][reg] * dv);
                    }
                } else if (EPI == 1) {
#pragma unroll
                    for (int j = 0; j < 4; ++j) {
                        int c = colBase + wc + (j << 4) + l16;
                        Cb[(size_t)r * Cout + c] = f2bf(swishf(acc[i][j][reg] + bv[j]));
                    }
                } else {
                    const unsigned short* res = (const unsigned short*)aux;
#pragma unroll
                    for (int j = 0; j < 4; ++j) {
                        int c = colBase + wc + (j << 4) + l16;
                        float o = swishf(acc[i][j][reg] + bv[j]) + bf2f(res[(size_t)r * HH + c]);
                        Cb[(size_t)r * HH + c] = f2bf(o);
                        if (writeF) Cf[(size_t)r * HH + c] = o;
                    }
                }
            }
        }
    }
}

// Wide-load gather: wave = 1 node; 16 lanes x 16 B cover a 256 B row; 4 edge-groups
// in flight per load instruction; butterfly shfl reduce; packed 16 B store.
// agg[d] = bf16( dinv[d] * (sum_src y[src] + y[d]) + cb )   (y bf16 row-major)
__global__ __launch_bounds__(256) void k_agg(const unsigned short* __restrict__ y,
                                             const int* __restrict__ rowptr,
                                             const int* __restrict__ col,
                                             const float* __restrict__ dinv,
                                             const float* __restrict__ cb,
                                             unsigned short* __restrict__ agg) {
    int w = threadIdx.x >> 6;
    int lane = threadIdx.x & 63;
    int d = blockIdx.x * 4 + w;
    if (d >= NN) return;
    int grp = lane >> 4;
    int l16 = lane & 15;
    const uint4* yv = (const uint4*)y;  // row = 16 uint4
    float acc[8];
#pragma unroll
    for (int j = 0; j < 8; ++j) acc[j] = 0.f;
    if (grp == 0) {
        uint4 v = yv[(size_t)d * 16 + l16];
        float2 p0 = bf2f2(v.x), p1 = bf2f2(v.y), p2 = bf2f2(v.z), p3 = bf2f2(v.w);
        acc[0] = p0.x; acc[1] = p0.y; acc[2] = p1.x; acc[3] = p1.y;
        acc[4] = p2.x; acc[5] = p2.y; acc[6] = p3.x; acc[7] = p3.y;
    }
    int beg = rowptr[d];
    int end = rowptr[d + 1];
    for (int e = beg + grp; e < end; e += 4) {
        int s = col[e];
        uint4 v = yv[(size_t)s * 16 + l16];
        float2 p0 = bf2f2(v.x), p1 = bf2f2(v.y), p2 = bf2f2(v.z), p3 = bf2f2(v.w);
        acc[0] += p0.x; acc[1] += p0.y; acc[2] += p1.x; acc[3] += p1.y;
        acc[4] += p2.x; acc[5] += p2.y; acc[6] += p3.x; acc[7] += p3.y;
    }
#pragma unroll
    for (int j = 0; j < 8; ++j) {
        acc[j] += __shfl_xor(acc[j], 16, 64);
        acc[j] += __shfl_xor(acc[j], 32, 64);
    }
    if (grp == 0) {
        float dv = dinv[d];
        float4 c0 = *(const float4*)(cb + l16 * 8);
        float4 c1 = *(const float4*)(cb + l16 * 8 + 4);
        float o[8];
        o[0] = acc[0] * dv + c0.x; o[1] = acc[1] * dv + c0.y;
        o[2] = acc[2] * dv + c0.z; o[3] = acc[3] * dv + c0.w;
        o[4] = acc[4] * dv + c1.x; o[5] = acc[5] * dv + c1.y;
        o[6] = acc[6] * dv + c1.z; o[7] = acc[7] * dv + c1.w;
        uint4 pk;
        pk.x = (unsigned)f2bf(o[0]) | ((unsigned)f2bf(o[1]) << 16);
        pk.y = (unsigned)f2bf(o[2]) | ((unsigned)f2bf(o[3]) << 16);
        pk.z = (unsigned)f2bf(o[4]) | ((unsigned)f2bf(o[5]) << 16);
        pk.w = (unsigned)f2bf(o[6]) | ((unsigned)f2bf(o[7]) << 16);
        *(uint4*)(agg + (size_t)d * HH + l16 * 8) = pk;
    }
}

// per-graph mean/rstd from bf16 agg; var = E[a^2] - ms*(2-ms)*mean^2
__global__ __launch_bounds__(512) void k_stats(const unsigned short* __restrict__ agg,
                                               const int* __restrict__ gptr,
                                               const float* __restrict__ ms,
                                               float* __restrict__ gmean,
                                               float* __restrict__ grstd) {
    __shared__ float s1[512];
    __shared__ float s2[512];
    int g = blockIdx.x;
    int t = threadIdx.x;
    int c = t & 127;
    int part = t >> 7;
    int beg = gptr[g];
    int end = gptr[g + 1];
    float S1 = 0.f, S2 = 0.f;
    for (int n = beg + part; n < end; n += 4) {
        float v = bf2f(agg[(size_t)n * HH + c]);
        S1 += v;
        S2 += v * v;
    }
    s1[t] = S1;
    s2[t] = S2;
    __syncthreads();
    if (part == 0) {
        S1 = (s1[c] + s1[c + 128]) + (s1[c + 256] + s1[c + 384]);
        S2 = (s2[c] + s2[c + 128]) + (s2[c + 256] + s2[c + 384]);
        int cnt = end - beg;
        float inv = 1.0f / (float)(cnt > 0 ? cnt : 1);
        float m = S1 * inv;
        float msc = ms[c];
        float var = S2 * inv - msc * (2.0f - msc) * m * m;
        gmean[g * HH + c] = m;
        grstd[g * HH + c] = rsqrtf(var + 1e-5f);
    }
}

__global__ void k_normswish(const unsigned short* __restrict__ agg,
                            const int* __restrict__ batch, const float* __restrict__ gamma,
                            const float* __restrict__ beta, const float* __restrict__ ms,
                            const float* __restrict__ gmean, const float* __restrict__ grstd,
                            unsigned short* __restrict__ ha) {
    int idx = blockIdx.x * blockDim.x + threadIdx.x;
    if (idx >= NN * 32) return;
    int n = idx >> 5;
    int c0 = (idx & 31) << 2;
    int g = batch[n];
    uint2 ain = *(const uint2*)(agg + (size_t)n * HH + c0);
    float2 a01 = bf2f2(ain.x);
    float2 a23 = bf2f2(ain.y);
    float av[4] = {a01.x, a01.y, a23.x, a23.y};
    unsigned short o[4];
#pragma unroll
    for (int j = 0; j < 4; ++j) {
        int c = c0 + j;
        float sub = av[j] - ms[c] * gmean[g * HH + c];
        float hn = gamma[c] * sub * grstd[g * HH + c] + beta[c];
        o[j] = f2bf(swishf(hn));
    }
    uint2 p;
    p.x = (unsigned)o[0] | ((unsigned)o[1] << 16);
    p.y = (unsigned)o[2] | ((unsigned)o[3] << 16);
    *(uint2*)(ha + (size_t)n * HH + c0) = p;
}

extern "C" void kernel_launch(void* const* d_in, const int* in_sizes, int n_in,
                              void* d_out, int out_size, void* d_ws, size_t ws_size,
                              hipStream_t stream) {
    const float* x = (const float*)d_in[0];
    const int* ei = (const int*)d_in[1];
    const int* batch = (const int*)d_in[2];
    const float* z_embed = (const float*)d_in[3];
    const float* extra_w = (const float*)d_in[4];
    const float* extra_b = (const float*)d_in[5];
    const float* conv_w = (const float*)d_in[6];
    const float* conv_b = (const float*)d_in[7];
    const float* gamma = (const float*)d_in[8];
    const float* beta = (const float*)d_in[9];
    const float* mean_scale = (const float*)d_in[10];
    const float* mlp_w1 = (const float*)d_in[11];
    const float* mlp_b1 = (const float*)d_in[12];
    const float* mlp_w2 = (const float*)d_in[13];
    const float* mlp_b2 = (const float*)d_in[14];
    float* h_out = (float*)d_out;

    char* wsB = (char*)d_ws;
    size_t off = 0;
    auto alloc = [&](size_t bytes) -> void* {
        void* p = (void*)(wsB + off);
        off = (off + bytes + 255) & ~(size_t)255;
        return p;
    };
    float* dinv = (float*)alloc((size_t)NN * 4);
    int* deg = (int*)alloc((size_t)NN * 4);
    int* cursor = (int*)alloc((size_t)NN * 4);
    int* rowptr = (int*)alloc((size_t)(NN + 1) * 4);
    int* bsum = (int*)alloc(128 * 4);
    int* boff = (int*)alloc(128 * 4);
    int* col = (int*)alloc((size_t)EE * 4);
    int* gptr = (int*)alloc((size_t)(GG + 1) * 4);
    float* gmean = (float*)alloc((size_t)GG * HH * 4);
    float* grstd = (float*)alloc((size_t)GG * HH * 4);
    unsigned short* wb =
        (unsigned short*)alloc((size_t)(LL * (HH * HH + MM * HH + HH * MM)) * 2);
    unsigned short* cwb = wb;
    unsigned short* w1b = wb + (size_t)LL * HH * HH;
    unsigned short* w2b = w1b + (size_t)LL * MM * HH;
    unsigned short* hb = (unsigned short*)alloc((size_t)NN * HH * 2);    // bf16 residual
    unsigned short* ybuf = (unsigned short*)alloc((size_t)NN * HH * 2);  // y_bf then ha_bf
    unsigned short* tb = (unsigned short*)alloc((size_t)NN * MM * 2);    // t bf16; aliases agg
    unsigned short* aggb = tb;  // agg bf16 [N,H] (consumed before t is written)

    hipMemsetAsync(deg, 0, (size_t)NN * 4, stream);
    hipMemsetAsync(cursor, 0, (size_t)NN * 4, stream);

    k_embed<<<(NN * 32 + 255) / 256, 256, 0, stream>>>(x, z_embed, extra_w, extra_b, hb);
    {
        int n1 = LL * HH * HH, n2 = LL * MM * HH, n3 = LL * HH * MM;
        int nt = n1 + n2 + n3;
        k_f2bf3<<<(nt + 255) / 256, 256, 0, stream>>>(conv_w, cwb, n1, mlp_w1, w1b, n2,
                                                      mlp_w2, w2b, n3);
    }
    k_degree_p<<<1024, 256, 0, stream>>>(ei + EE, deg);
    k_dinv<<<(NN + 255) / 256, 256, 0, stream>>>(deg, dinv);
    k_scan1<<<SCAN_NB, 256, 0, stream>>>(deg, bsum);
    k_scan2<<<1, 128, 0, stream>>>(bsum, boff);
    k_scan3<<<SCAN_NB, 256, 0, stream>>>(deg, boff, rowptr);
    k_fill_p<<<1024, 256, 0, stream>>>(ei, rowptr, cursor, col);
    k_gptr<<<(NN + 255) / 256, 256, 0, stream>>>(batch, gptr);

    dim3 g1((NN + 127) / 128, 1);
    dim3 g2((NN + 127) / 128, 2);
    for (int i = 0; i < LL; ++i) {
        k_gemm<HH, 0><<<g1, 256, 0, stream>>>(hb, cwb + (size_t)i * HH * HH, nullptr, dinv,
                                              nullptr, ybuf, 0);
        k_agg<<<(NN + 3) / 4, 256, 0, stream>>>(ybuf, rowptr, col, dinv,
                                                conv_b + (size_t)i * HH, aggb);
        k_stats<<<GG, 512, 0, stream>>>(aggb, gptr, mean_scale + (size_t)i * HH, gmean, grstd);
        k_normswish<<<(NN * 32 + 255) / 256, 256, 0, stream>>>(
            aggb, batch, gamma + (size_t)i * HH, beta + (size_t)i * HH,
            mean_scale + (size_t)i * HH, gmean, grstd, ybuf);
        k_gemm<HH, 1><<<g2, 256, 0, stream>>>(ybuf, w1b + (size_t)i * MM * HH,
                                              mlp_b1 + (size_t)i * MM, nullptr, nullptr, tb, 0);
        k_gemm<MM, 2><<<g1, 256, 0, stream>>>(tb, w2b + (size_t)i * HH * MM,
                                              mlp_b2 + (size_t)i * HH, hb, h_out, hb,
                                              i == LL - 1 ? 1 : 0);
    }
}